// Round 3
// baseline (4981.266 us; speedup 1.0000x reference)
//
#include <hip/hip_runtime.h>
#include <math.h>

#define T_ 64
#define B_ 256
#define N_ 256
#define M_ 128
#define H_ 1024
#define I_ 128
#define NB 256
#define NT 1024
#define MSTR 132          // mem row stride (floats); 33*4B banks -> spread
#define EPSF 1e-8f

// ---- ws layout (uint offsets) ----
#define WS_WCX 0                 // [1024 h][64 k2]  Wc x-part, K-pairs
#define WS_WCR 65536             // [1024 h][64 k2]  Wc rd-part
#define WS_W2P 131072            // [512 c][512 k2]  Wk0|Wk1|We|Wa
#define WS_WOP 393216            // [128 c][64 m2]   Wo
#define WS_WSM 401408            // [12 d][512 k2]   beta,g,gamma,shift
#define WS_XC  407552            // _Float16 xc[T*B][H] (optional, 32 MB)
#define WS_BYTES_NEEDED ((size_t)(407552 + 8388608) * 4)

typedef _Float16 h2_t __attribute__((ext_vector_type(2)));

__device__ __forceinline__ float fdot2(unsigned a, unsigned b, float c) {
  union { unsigned u; h2_t h; } ua, ub;
  ua.u = a; ub.u = b;
  return __builtin_amdgcn_fdot2(ua.h, ub.h, c, false);
}
__device__ __forceinline__ unsigned packh2(float a, float b) {
  union { h2_t h; unsigned u; } v;
  v.h = h2_t{(_Float16)a, (_Float16)b};
  return v.u;
}
__device__ __forceinline__ float dot4(uint4 w, uint4 h, float acc) {
  acc = fdot2(w.x, h.x, acc); acc = fdot2(w.y, h.y, acc);
  acc = fdot2(w.z, h.z, acc); acc = fdot2(w.w, h.w, acc);
  return acc;
}
__device__ __forceinline__ float wave_rsum(float v) {
#pragma unroll
  for (int o = 32; o > 0; o >>= 1) v += __shfl_xor(v, o, 64);
  return v;
}
__device__ __forceinline__ float wave_rmax(float v) {
#pragma unroll
  for (int o = 32; o > 0; o >>= 1) v = fmaxf(v, __shfl_xor(v, o, 64));
  return v;
}

// ============ pack: fp32 weights -> fp16 K-pair-packed, column-major rows ============
__global__ void ntm_pack(const float* __restrict__ Wc, const float* __restrict__ Wk,
                         const float* __restrict__ Wb, const float* __restrict__ Wg,
                         const float* __restrict__ Wsf, const float* __restrict__ Wgm,
                         const float* __restrict__ We, const float* __restrict__ Wa,
                         const float* __restrict__ Wo,
                         unsigned* __restrict__ wsu)
{
  const int total = 65536 + 65536 + 262144 + 8192 + 6144;
  for (int i = blockIdx.x * blockDim.x + threadIdx.x; i < total;
       i += gridDim.x * blockDim.x) {
    if (i < 65536) {
      int h = i >> 6, k2 = i & 63;
      wsu[WS_WCX + i] = packh2(Wc[(size_t)(2 * k2) * H_ + h], Wc[(size_t)(2 * k2 + 1) * H_ + h]);
    } else if (i < 131072) {
      int u = i - 65536, h = u >> 6, k2 = u & 63;
      wsu[WS_WCR + u] = packh2(Wc[(size_t)(128 + 2 * k2) * H_ + h],
                               Wc[(size_t)(129 + 2 * k2) * H_ + h]);
    } else if (i < 131072 + 262144) {
      int u = i - 131072, c = u >> 9, k2 = u & 511;
      int k0 = 2 * k2, k1 = 2 * k2 + 1;
      float v0, v1;
      if (c < 128)      { v0 = Wk[(size_t)k0 * M_ + c];           v1 = Wk[(size_t)k1 * M_ + c]; }
      else if (c < 256) { v0 = Wk[(size_t)H_ * M_ + (size_t)k0 * M_ + (c - 128)];
                          v1 = Wk[(size_t)H_ * M_ + (size_t)k1 * M_ + (c - 128)]; }
      else if (c < 384) { v0 = We[(size_t)k0 * M_ + (c - 256)];   v1 = We[(size_t)k1 * M_ + (c - 256)]; }
      else              { v0 = Wa[(size_t)k0 * M_ + (c - 384)];   v1 = Wa[(size_t)k1 * M_ + (c - 384)]; }
      wsu[WS_W2P + u] = packh2(v0, v1);
    } else if (i < 131072 + 262144 + 8192) {
      int u = i - 131072 - 262144, c = u >> 6, m2 = u & 63;
      wsu[WS_WOP + u] = packh2(Wo[(size_t)(2 * m2) * I_ + c], Wo[(size_t)(2 * m2 + 1) * I_ + c]);
    } else {
      int u = i - 131072 - 262144 - 8192, d = u >> 9, k2 = u & 511;
      int k0 = 2 * k2, k1 = 2 * k2 + 1;
      float v0, v1;
      if (d < 2)      { v0 = Wb[d * H_ + k0];        v1 = Wb[d * H_ + k1]; }
      else if (d < 4) { v0 = Wg[(d - 2) * H_ + k0];  v1 = Wg[(d - 2) * H_ + k1]; }
      else if (d < 6) { v0 = Wgm[(d - 4) * H_ + k0]; v1 = Wgm[(d - 4) * H_ + k1]; }
      else if (d < 9) { v0 = Wsf[k0 * 3 + (d - 6)];  v1 = Wsf[k1 * 3 + (d - 6)]; }
      else            { v0 = Wsf[3 * H_ + k0 * 3 + (d - 9)]; v1 = Wsf[3 * H_ + k1 * 3 + (d - 9)]; }
      wsu[WS_WSM + u] = packh2(v0, v1);
    }
  }
}

// ============ xc precompute: xc[t,b,h] = x[t,b,:] @ Wc_x (fp16 out) ============
__global__ __launch_bounds__(256)
void ntm_xc(const float* __restrict__ x, const unsigned* __restrict__ wsu,
            unsigned* __restrict__ wsout)
{
  __shared__ __align__(16) _Float16 xt[16 * 128];
  const int tid = threadIdx.x;
  const size_t row0 = (size_t)blockIdx.x * 16;
  for (int i = tid; i < 16 * 128; i += 256)
    xt[i] = (_Float16)x[(row0 + (i >> 7)) * I_ + (i & 127)];
  __syncthreads();
  _Float16* xc16 = (_Float16*)(wsout + WS_XC);
  const uint4* xt4 = (const uint4*)xt;
  for (int cq = 0; cq < 4; ++cq) {
    const int col = cq * 256 + tid;
    const uint4* w4 = (const uint4*)(wsu + WS_WCX) + col * 16;
    float acc[16];
#pragma unroll
    for (int r = 0; r < 16; ++r) acc[r] = 0.f;
#pragma unroll 4
    for (int k4 = 0; k4 < 16; ++k4) {
      uint4 w = w4[k4];
#pragma unroll
      for (int r = 0; r < 16; ++r)
        acc[r] = dot4(w, xt4[r * 16 + k4], acc[r]);
    }
#pragma unroll
    for (int r = 0; r < 16; ++r)
      xc16[(row0 + r) * H_ + col] = (_Float16)acc[r];
  }
}

// ============ main: one persistent block (1024 thr) per batch element ============
__global__ __launch_bounds__(NT)
void ntm_main(const float* __restrict__ x,
              const float* __restrict__ bc,  const float* __restrict__ bk,
              const float* __restrict__ bbv, const float* __restrict__ bg,
              const float* __restrict__ bsf, const float* __restrict__ bgm,
              const float* __restrict__ be,  const float* __restrict__ ba,
              const float* __restrict__ bo,
              const float* __restrict__ mem0, const float* __restrict__ ww0,
              const float* __restrict__ rw0,  const float* __restrict__ rd0,
              const unsigned* __restrict__ wsu,
              float* __restrict__ out, int useXc)
{
  __shared__ __align__(16) float mem[N_ * MSTR];     // 135168 B
  __shared__ __align__(16) _Float16 ht16[H_];        // 2048  (pairs (2k,2k+1) = contiguous)
  __shared__ __align__(16) _Float16 rd16[M_];        // 256
  __shared__ __align__(16) _Float16 x16[M_];         // 256   (fallback path)
  __shared__ __align__(16) float prevw[2 * N_];      // 2048  ww | rw
  __shared__ __align__(16) float mnv[N_];            // 1024
  __shared__ __align__(16) float ksh[2 * M_];        // 1024
  __shared__ __align__(16) float eah[2 * M_];        // 1024
  __shared__ __align__(16) float wlog[2 * N_];       // 2048
  __shared__ __align__(16) float wtmp[2 * N_];       // 2048
  __shared__ __align__(16) float redU[2048];         // 8192
  __shared__ __align__(16) float sdots[24];
  __shared__ __align__(16) float scal[32];
  __shared__ __align__(16) float bcL[H_];            // 4096
  __shared__ __align__(16) float bkL[256];
  __shared__ __align__(16) float beL[128];
  __shared__ __align__(16) float baL[128];
  __shared__ __align__(16) float boL[128];
  __shared__ __align__(16) float sb[16];

  const int tid = threadIdx.x;
  const int b = blockIdx.x;
  const _Float16* xcg = (const _Float16*)(wsu + WS_XC);

  // ---------- prologue ----------
  for (int i = tid; i < N_ * M_; i += NT)
    mem[(i >> 7) * MSTR + (i & 127)] = mem0[i];
  bcL[tid] = bc[tid];
  if (tid < 256) bkL[tid] = bk[tid];
  if (tid < 128) { beL[tid] = be[tid]; baL[tid] = ba[tid]; boL[tid] = bo[tid]; }
  if (tid < 12) {
    float v;
    if (tid < 2) v = bbv[tid];
    else if (tid < 4) v = bg[tid - 2];
    else if (tid < 6) v = bgm[tid - 4];
    else v = bsf[tid - 6];
    sb[tid] = v;
  }
  if (tid < 512) wlog[tid] = (tid < 256) ? ww0[tid] : rw0[tid - 256];
  __syncthreads();
  if (tid < 256) {
    float s = 0.f;
#pragma unroll 8
    for (int m = 0; m < M_; ++m) { float v = mem[tid * MSTR + m]; s += v * v; }
    mnv[tid] = fmaxf(sqrtf(s), EPSF);
  }
  {
    int wv = tid >> 6, ln = tid & 63;
    if (wv < 2) {
      float l0 = wlog[wv * N_ + ln], l1 = wlog[wv * N_ + 64 + ln],
            l2 = wlog[wv * N_ + 128 + ln], l3 = wlog[wv * N_ + 192 + ln];
      float mx = wave_rmax(fmaxf(fmaxf(l0, l1), fmaxf(l2, l3)));
      float e0 = __expf(l0 - mx), e1 = __expf(l1 - mx), e2 = __expf(l2 - mx), e3 = __expf(l3 - mx);
      float sm = wave_rsum(e0 + e1 + e2 + e3);
      wlog[wv * N_ + ln] = e0; wlog[wv * N_ + 64 + ln] = e1;
      wlog[wv * N_ + 128 + ln] = e2; wlog[wv * N_ + 192 + ln] = e3;
      if (ln == 0) scal[30 + wv] = 1.f / sm;
    }
  }
  __syncthreads();
  if (tid < 512) prevw[tid] = wlog[tid] * scal[30 + (tid >> 8)];
  if (tid < 64)
    ((unsigned*)rd16)[tid] = packh2(rd0[2 * tid], rd0[2 * tid + 1]);
  if (!useXc && tid >= 64 && tid < 128) {
    int k = tid - 64;
    ((unsigned*)x16)[k] = packh2(x[(size_t)b * I_ + 2 * k], x[(size_t)b * I_ + 2 * k + 1]);
  }
  __syncthreads();

  // ---------- time loop ----------
  for (int t = 0; t < T_; ++t) {
    // S1: phase A (ht col per thread) + C12 of step t-1 (Wo partials)
    {
      const int j = tid;
      float acc;
      if (useXc) {
        acc = (float)xcg[((size_t)t * B_ + b) * H_ + j];
      } else {
        acc = 0.f;
        const uint4* wx = (const uint4*)(wsu + WS_WCX) + j * 16;
        const uint4* xp4 = (const uint4*)x16;
#pragma unroll 4
        for (int k4 = 0; k4 < 16; ++k4) acc = dot4(wx[k4], xp4[k4], acc);
      }
      const uint4* wr = (const uint4*)(wsu + WS_WCR) + j * 16;
      const uint4* rp4 = (const uint4*)rd16;
#pragma unroll 4
      for (int k4 = 0; k4 < 16; ++k4) acc = dot4(wr[k4], rp4[k4], acc);
      ht16[j] = (_Float16)tanhf(acc + bcL[j]);
      if (t > 0) {           // C12(t-1): out partials = rd(t-1) @ Wo
        int c = tid & 127, q = tid >> 7;
        const uint4* wo4 = (const uint4*)(wsu + WS_WOP) + c * 16 + q * 2;
        const uint4* rq4 = ((const uint4*)rd16) + q * 2;
        float s = dot4(wo4[0], rq4[0], 0.f);
        s = dot4(wo4[1], rq4[1], s);
        redU[1024 + q * 128 + c] = s;
      }
    }
    __syncthreads();

    // S3: phase B partials (c=tid&511, K-half=tid>>9) + out-write(t-1)
    {
      const int c = tid & 511, half = tid >> 9;
      const uint4* w4 = (const uint4*)(wsu + WS_W2P) + c * 128 + half * 64;
      const uint4* h4 = ((const uint4*)ht16) + half * 64;
      float a0 = 0.f, a1 = 0.f, a2 = 0.f, a3 = 0.f;
#pragma unroll 2
      for (int k4 = 0; k4 < 64; k4 += 4) {
        a0 = dot4(w4[k4],     h4[k4],     a0);
        a1 = dot4(w4[k4 + 1], h4[k4 + 1], a1);
        a2 = dot4(w4[k4 + 2], h4[k4 + 2], a2);
        a3 = dot4(w4[k4 + 3], h4[k4 + 3], a3);
      }
      redU[half * 512 + c] = (a0 + a1) + (a2 + a3);
      if (tid < 128 && t > 0) {
        float o = boL[tid];
#pragma unroll
        for (int q = 0; q < 8; ++q) o += redU[1024 + q * 128 + tid];
        out[((size_t)(t - 1) * B_ + b) * I_ + tid] = o;
      }
    }
    __syncthreads();

    // S4: B finalize + activations (tid<512) | C1 small-dot halves (waves 8-15)
    {
      if (tid < 512) {
        float v = redU[tid] + redU[512 + tid];
        if (tid < 256)      ksh[tid] = fmaxf(v + bkL[tid], 0.f);
        else if (tid < 384) eah[tid - 256] = 1.f / (1.f + __expf(-(v + beL[tid - 256])));
        else                eah[tid - 256] = 1.f / (1.f + __expf(-(v + baL[tid - 384])));
      } else {
        int wv = (tid >> 6) - 8, ln = tid & 63;
#pragma unroll
        for (int i = 0; i < 3; ++i) {
          int hd = wv * 3 + i;           // 24 half-dots
          int d = hd >> 1, half = hd & 1;
          const uint4* wp = (const uint4*)(wsu + WS_WSM) + d * 128 + half * 64;
          float s = dot4(wp[ln], ((const uint4*)ht16)[half * 64 + ln], 0.f);
          s = wave_rsum(s);
          if (ln == 0) sdots[hd] = s;
        }
      }
    }
    __syncthreads();

    // S5: C2 scalar finalize (tid 0) | key norms (waves 1,2)
    {
      if (tid == 0) {
        for (int h = 0; h < 2; ++h) {
          float Sb = sdots[2 * h] + sdots[2 * h + 1];
          float Sg = sdots[2 * (2 + h)] + sdots[2 * (2 + h) + 1];
          float Sgm = sdots[2 * (4 + h)] + sdots[2 * (4 + h) + 1];
          float rb = Sb + sb[h];
          scal[16 + h] = (rb > 20.f) ? rb : log1pf(__expf(rb));
          scal[18 + h] = 1.f / (1.f + __expf(-(Sg + sb[2 + h])));
          scal[20 + h] = fmaxf(Sgm + sb[4 + h], 0.f) + 1.f;
          float s0 = sdots[2 * (6 + 3 * h)] + sdots[2 * (6 + 3 * h) + 1] + sb[6 + 3 * h];
          float s1 = sdots[2 * (7 + 3 * h)] + sdots[2 * (7 + 3 * h) + 1] + sb[7 + 3 * h];
          float s2 = sdots[2 * (8 + 3 * h)] + sdots[2 * (8 + 3 * h) + 1] + sb[8 + 3 * h];
          float mx = fmaxf(s0, fmaxf(s1, s2));
          float e0 = __expf(s0 - mx), e1 = __expf(s1 - mx), e2 = __expf(s2 - mx);
          float inv = 1.f / (e0 + e1 + e2);
          scal[22 + 3 * h] = e0 * inv; scal[23 + 3 * h] = e1 * inv; scal[24 + 3 * h] = e2 * inv;
        }
      } else if (tid >= 64 && tid < 192) {
        int h = (tid >> 6) - 1, ln = tid & 63;
        float v0 = ksh[h * 128 + ln], v1 = ksh[h * 128 + 64 + ln];
        float s = wave_rsum(v0 * v0 + v1 * v1);
        if (ln == 0) scal[12 + h] = fmaxf(sqrtf(s), EPSF);
      }
    }
    __syncthreads();

    // S6: C3 cosine logits (thread = (head, row, M-half); shfl pair-reduce)
    {
      int half = tid & 1, r = (tid >> 1) & 255, h = tid >> 9;
      const float4* kp = (const float4*)&ksh[h * 128 + half * 64];
      const float4* mp = (const float4*)&mem[r * MSTR + half * 64];
      float dot = 0.f;
#pragma unroll
      for (int i = 0; i < 16; ++i) {
        float4 kv = kp[i], mv = mp[i];
        dot += kv.x * mv.x + kv.y * mv.y + kv.z * mv.z + kv.w * mv.w;
      }
      dot += __shfl_xor(dot, 1, 64);
      if (half == 0)
        wlog[h * 256 + r] = scal[16 + h] * (dot / (scal[12 + h] * mnv[r]));
    }
    __syncthreads();

    // S7: C4 content softmax (waves 0,1)
    {
      int wv = tid >> 6, ln = tid & 63;
      if (wv < 2) {
        float l0 = wlog[wv * N_ + ln], l1 = wlog[wv * N_ + 64 + ln],
              l2 = wlog[wv * N_ + 128 + ln], l3 = wlog[wv * N_ + 192 + ln];
        float mx = wave_rmax(fmaxf(fmaxf(l0, l1), fmaxf(l2, l3)));
        float e0 = __expf(l0 - mx), e1 = __expf(l1 - mx), e2 = __expf(l2 - mx), e3 = __expf(l3 - mx);
        float sm = wave_rsum(e0 + e1 + e2 + e3);
        wlog[wv * N_ + ln] = e0; wlog[wv * N_ + 64 + ln] = e1;
        wlog[wv * N_ + 128 + ln] = e2; wlog[wv * N_ + 192 + ln] = e3;
        if (ln == 0) scal[30 + wv] = 1.f / sm;
      }
    }
    __syncthreads();

    // S8: C5 interpolate
    if (tid < 512) {
      int h = tid >> 8;
      float g = scal[18 + h];
      wtmp[tid] = g * wlog[tid] * scal[30 + h] + (1.f - g) * prevw[tid];
    }
    __syncthreads();

    // S9: C6 circular shift + sharpen
    if (tid < 512) {
      int h = tid >> 8, n = tid & 255;
      float v = scal[22 + 3 * h] * wtmp[h * N_ + ((n + 255) & 255)]
              + scal[23 + 3 * h] * wtmp[h * N_ + n]
              + scal[24 + 3 * h] * wtmp[h * N_ + ((n + 1) & 255)];
      wlog[tid] = __powf(v, scal[20 + h]);
    }
    __syncthreads();

    // S10: C7 normalization sums
    {
      int wv = tid >> 6, ln = tid & 63;
      if (wv < 2) {
        float s = wlog[wv * N_ + ln] + wlog[wv * N_ + 64 + ln]
                + wlog[wv * N_ + 128 + ln] + wlog[wv * N_ + 192 + ln];
        s = wave_rsum(s);
        if (ln == 0) scal[14 + wv] = 1.f / s;
      }
    }
    __syncthreads();

    // S11: C9 memory update (thread = (row, M-quarter)) + sq partials + prevw(ww)
    {
      int n = tid & 255, q = tid >> 8;
      float wwn = wlog[n] * scal[14];
      float* mrow = &mem[n * MSTR + q * 32];
      const float4* ep = (const float4*)&eah[q * 32];
      const float4* ap = (const float4*)&eah[128 + q * 32];
      float sq = 0.f;
#pragma unroll
      for (int i = 0; i < 8; ++i) {
        float4 mv = *(float4*)&mrow[i * 4];
        float4 ev = ep[i], av = ap[i];
        mv.x = mv.x * (1.f - wwn * ev.x) + wwn * av.x;
        mv.y = mv.y * (1.f - wwn * ev.y) + wwn * av.y;
        mv.z = mv.z * (1.f - wwn * ev.z) + wwn * av.z;
        mv.w = mv.w * (1.f - wwn * ev.w) + wwn * av.w;
        sq += mv.x * mv.x + mv.y * mv.y + mv.z * mv.z + mv.w * mv.w;
        *(float4*)&mrow[i * 4] = mv;
      }
      redU[1024 + q * 256 + n] = sq;
      if (q == 0) prevw[n] = wwn;
    }
    __syncthreads();

    // S12: C10 rd partials (thread = (m, 8-way n-group))
    {
      int m = tid & 127, g = tid >> 7;
      const float* basep = &mem[g * 32 * MSTR + m];
      float acc = 0.f;
#pragma unroll 8
      for (int i = 0; i < 32; ++i)
        acc += wlog[256 + g * 32 + i] * basep[i * MSTR];
      redU[g * 128 + m] = acc;
    }
    __syncthreads();

    // S13: rd finalize+pack | prevw(rw) | mnv | next-x pack (fallback)
    {
      if (tid < 64) {
        float r0 = 0.f, r1 = 0.f;
#pragma unroll
        for (int g = 0; g < 8; ++g) {
          r0 += redU[g * 128 + 2 * tid];
          r1 += redU[g * 128 + 2 * tid + 1];
        }
        ((unsigned*)rd16)[tid] = packh2(r0 * scal[15], r1 * scal[15]);
      } else if (tid >= 256 && tid < 512) {
        int n = tid - 256;
        prevw[256 + n] = wlog[256 + n] * scal[15];
      } else if (tid >= 512 && tid < 768) {
        int n = tid - 512;
        float s = redU[1024 + n] + redU[1280 + n] + redU[1536 + n] + redU[1792 + n];
        mnv[n] = fmaxf(sqrtf(s), EPSF);
      } else if (!useXc && tid >= 768 && tid < 832 && t < T_ - 1) {
        int k = tid - 768;
        const float* xr = &x[((size_t)(t + 1) * B_ + b) * I_];
        ((unsigned*)x16)[k] = packh2(xr[2 * k], xr[2 * k + 1]);
      }
    }
    __syncthreads();
  }

  // ---------- epilogue: C12/C13 for t = T-1 ----------
  {
    int c = tid & 127, q = tid >> 7;
    const uint4* wo4 = (const uint4*)(wsu + WS_WOP) + c * 16 + q * 2;
    const uint4* rq4 = ((const uint4*)rd16) + q * 2;
    float s = dot4(wo4[0], rq4[0], 0.f);
    s = dot4(wo4[1], rq4[1], s);
    redU[1024 + q * 128 + c] = s;
  }
  __syncthreads();
  if (tid < 128) {
    float o = boL[tid];
#pragma unroll
    for (int q = 0; q < 8; ++q) o += redU[1024 + q * 128 + tid];
    out[((size_t)(T_ - 1) * B_ + b) * I_ + tid] = o;
  }
}

extern "C" void kernel_launch(void* const* d_in, const int* in_sizes, int n_in,
                              void* d_out, int out_size, void* d_ws, size_t ws_size,
                              hipStream_t stream) {
  (void)in_sizes; (void)n_in; (void)out_size;

  const float* x    = (const float*)d_in[0];
  const float* Wc   = (const float*)d_in[1];
  const float* bc   = (const float*)d_in[2];
  const float* Wk   = (const float*)d_in[3];
  const float* bk   = (const float*)d_in[4];
  const float* Wb   = (const float*)d_in[5];
  const float* bbv  = (const float*)d_in[6];
  const float* Wg   = (const float*)d_in[7];
  const float* bg   = (const float*)d_in[8];
  const float* Wsf  = (const float*)d_in[9];
  const float* bsf  = (const float*)d_in[10];
  const float* Wgm  = (const float*)d_in[11];
  const float* bgm  = (const float*)d_in[12];
  const float* We   = (const float*)d_in[13];
  const float* be   = (const float*)d_in[14];
  const float* Wa   = (const float*)d_in[15];
  const float* ba   = (const float*)d_in[16];
  const float* Wo   = (const float*)d_in[17];
  const float* bo   = (const float*)d_in[18];
  const float* mem0 = (const float*)d_in[19];
  const float* ww0  = (const float*)d_in[20];
  const float* rw0  = (const float*)d_in[21];
  const float* rd0  = (const float*)d_in[22];
  float* out = (float*)d_out;
  unsigned* wsu = (unsigned*)d_ws;

  const int useXc = (ws_size >= WS_BYTES_NEEDED) ? 1 : 0;

  ntm_pack<<<dim3(512), dim3(256), 0, stream>>>(Wc, Wk, Wb, Wg, Wsf, Wgm, We, Wa, Wo, wsu);
  if (useXc)
    ntm_xc<<<dim3(T_ * B_ / 16), dim3(256), 0, stream>>>(x, wsu, wsu);
  ntm_main<<<dim3(NB), dim3(NT), 0, stream>>>(x, bc, bk, bbv, bg, bsf, bgm, be, ba, bo,
                                              mem0, ww0, rw0, rd0, wsu, out, useXc);
}

// Round 4
// 1374.604 us; speedup vs baseline: 3.6238x; 3.6238x over previous
//
#include <hip/hip_runtime.h>
#include <math.h>

#define T_ 64
#define B_ 256
#define N_ 256
#define M_ 128
#define H_ 1024
#define I_ 128
#define NB 256
#define NT 1024
#define MSTR 132          // mem row stride (floats)
#define EPSF 1e-8f

// ---- ws layout (uint offsets). All big weights THREAD-MAJOR: [k-chunk][col],
// so consecutive lanes read consecutive 16B -> coalesced wave transactions. ----
#define WS_WCX 0                 // [16 k4][1024 h] uint4  (Wc x-part)
#define WS_WCR 65536             // [16 k4][1024 h] uint4  (Wc rd-part)
#define WS_W2P 131072            // [128 k4][512 c] uint4  (Wk0|Wk1|We|Wa)
#define WS_WOP 393216            // [16 k4][128 c]  uint4  (Wo)
#define WS_WSM 401408            // [12 d][512 k2]  uint   (beta,g,gamma,shift)
#define WS_XC  407552            // _Float16 xc[T*B][H] (32 MB)
#define WS_BYTES_NEEDED ((size_t)(407552 + 8388608) * 4)

typedef _Float16 h2_t __attribute__((ext_vector_type(2)));

__device__ __forceinline__ float fdot2(unsigned a, unsigned b, float c) {
  union { unsigned u; h2_t h; } ua, ub;
  ua.u = a; ub.u = b;
  return __builtin_amdgcn_fdot2(ua.h, ub.h, c, false);
}
__device__ __forceinline__ unsigned packh2(float a, float b) {
  union { h2_t h; unsigned u; } v;
  v.h = h2_t{(_Float16)a, (_Float16)b};
  return v.u;
}
__device__ __forceinline__ float dot4(uint4 w, uint4 h, float acc) {
  acc = fdot2(w.x, h.x, acc); acc = fdot2(w.y, h.y, acc);
  acc = fdot2(w.z, h.z, acc); acc = fdot2(w.w, h.w, acc);
  return acc;
}
__device__ __forceinline__ float wave_rsum(float v) {
#pragma unroll
  for (int o = 32; o > 0; o >>= 1) v += __shfl_xor(v, o, 64);
  return v;
}
__device__ __forceinline__ float wave_rmax(float v) {
#pragma unroll
  for (int o = 32; o > 0; o >>= 1) v = fmaxf(v, __shfl_xor(v, o, 64));
  return v;
}

// ============ pack: fp32 -> fp16, thread-major chunked layouts ============
// uint4 chunk k4 covers K-values [8*k4, 8*k4+8); pairs are K-consecutive, so
// plain contiguous fp16 activation arrays match the packing.
__global__ void ntm_pack(const float* __restrict__ Wc, const float* __restrict__ Wk,
                         const float* __restrict__ Wb, const float* __restrict__ Wg,
                         const float* __restrict__ Wsf, const float* __restrict__ Wgm,
                         const float* __restrict__ We, const float* __restrict__ Wa,
                         const float* __restrict__ Wo,
                         unsigned* __restrict__ wsu)
{
  const int total = 407552;
  for (int i = blockIdx.x * blockDim.x + threadIdx.x; i < total;
       i += gridDim.x * blockDim.x) {
    if (i < 65536) {                       // WCX: q4 = k4*1024 + h
      int jm = i & 3, q4 = i >> 2, k4 = q4 >> 10, h = q4 & 1023;
      int k0 = k4 * 8 + 2 * jm;
      wsu[WS_WCX + i] = packh2(Wc[(size_t)k0 * H_ + h], Wc[(size_t)(k0 + 1) * H_ + h]);
    } else if (i < 131072) {               // WCR: rd-part rows 128..255
      int u = i - 65536;
      int jm = u & 3, q4 = u >> 2, k4 = q4 >> 10, h = q4 & 1023;
      int k0 = 128 + k4 * 8 + 2 * jm;
      wsu[WS_WCR + u] = packh2(Wc[(size_t)k0 * H_ + h], Wc[(size_t)(k0 + 1) * H_ + h]);
    } else if (i < 393216) {               // W2P: q4 = k4*512 + c
      int u = i - 131072;
      int jm = u & 3, q4 = u >> 2, k4 = q4 >> 9, c = q4 & 511;
      int k0 = k4 * 8 + 2 * jm, k1 = k0 + 1;
      float v0, v1;
      if (c < 128)      { v0 = Wk[(size_t)k0 * M_ + c];           v1 = Wk[(size_t)k1 * M_ + c]; }
      else if (c < 256) { v0 = Wk[(size_t)H_ * M_ + (size_t)k0 * M_ + (c - 128)];
                          v1 = Wk[(size_t)H_ * M_ + (size_t)k1 * M_ + (c - 128)]; }
      else if (c < 384) { v0 = We[(size_t)k0 * M_ + (c - 256)];   v1 = We[(size_t)k1 * M_ + (c - 256)]; }
      else              { v0 = Wa[(size_t)k0 * M_ + (c - 384)];   v1 = Wa[(size_t)k1 * M_ + (c - 384)]; }
      wsu[WS_W2P + u] = packh2(v0, v1);
    } else if (i < 401408) {               // WOP: q4 = k4*128 + c
      int u = i - 393216;
      int jm = u & 3, q4 = u >> 2, k4 = q4 >> 7, c = q4 & 127;
      int m0 = k4 * 8 + 2 * jm;
      wsu[WS_WOP + u] = packh2(Wo[(size_t)m0 * I_ + c], Wo[(size_t)(m0 + 1) * I_ + c]);
    } else {                               // WSM: [d][512 k2] (wave-coalesced reads)
      int u = i - 401408, d = u >> 9, k2 = u & 511;
      int k0 = 2 * k2, k1 = 2 * k2 + 1;
      float v0, v1;
      if (d < 2)      { v0 = Wb[d * H_ + k0];        v1 = Wb[d * H_ + k1]; }
      else if (d < 4) { v0 = Wg[(d - 2) * H_ + k0];  v1 = Wg[(d - 2) * H_ + k1]; }
      else if (d < 6) { v0 = Wgm[(d - 4) * H_ + k0]; v1 = Wgm[(d - 4) * H_ + k1]; }
      else if (d < 9) { v0 = Wsf[k0 * 3 + (d - 6)];  v1 = Wsf[k1 * 3 + (d - 6)]; }
      else            { v0 = Wsf[3 * H_ + k0 * 3 + (d - 9)]; v1 = Wsf[3 * H_ + k1 * 3 + (d - 9)]; }
      wsu[WS_WSM + u] = packh2(v0, v1);
    }
  }
}

// ============ xc precompute: xc[t,b,:] = x[t,b,:] @ Wc_x (fp16) ============
__global__ __launch_bounds__(256)
void ntm_xc(const float* __restrict__ x, const unsigned* __restrict__ wsu,
            unsigned* __restrict__ wsout)
{
  __shared__ __align__(16) _Float16 xt[16 * 128];
  const int tid = threadIdx.x;
  const size_t row0 = (size_t)blockIdx.x * 16;
  for (int i = tid; i < 16 * 128; i += 256)
    xt[i] = (_Float16)x[(row0 + (i >> 7)) * I_ + (i & 127)];
  __syncthreads();
  _Float16* xc16 = (_Float16*)(wsout + WS_XC);
  const uint4* xt4 = (const uint4*)xt;
  const uint4* w4 = (const uint4*)(wsu + WS_WCX);
  for (int cq = 0; cq < 4; ++cq) {
    const int col = cq * 256 + tid;
    float acc[16];
#pragma unroll
    for (int r = 0; r < 16; ++r) acc[r] = 0.f;
#pragma unroll 4
    for (int k4 = 0; k4 < 16; ++k4) {
      uint4 w = w4[k4 * 1024 + col];       // coalesced across tid
#pragma unroll
      for (int r = 0; r < 16; ++r)
        acc[r] = dot4(w, xt4[r * 16 + k4], acc[r]);
    }
#pragma unroll
    for (int r = 0; r < 16; ++r)
      xc16[(row0 + r) * H_ + col] = (_Float16)acc[r];
  }
}

// ============ main: one persistent 1024-thread block per batch element ============
__global__ __launch_bounds__(NT)
void ntm_main(const float* __restrict__ x,
              const float* __restrict__ bc,  const float* __restrict__ bk,
              const float* __restrict__ bbv, const float* __restrict__ bg,
              const float* __restrict__ bsf, const float* __restrict__ bgm,
              const float* __restrict__ be,  const float* __restrict__ ba,
              const float* __restrict__ bo,
              const float* __restrict__ mem0, const float* __restrict__ ww0,
              const float* __restrict__ rw0,  const float* __restrict__ rd0,
              const unsigned* __restrict__ wsu,
              float* __restrict__ out, int useXc)
{
  __shared__ __align__(16) float mem[N_ * MSTR];     // 135168 B
  __shared__ __align__(16) _Float16 ht16[H_];        // 2048 (K-contiguous)
  __shared__ __align__(16) _Float16 rd16[M_];        // 256
  __shared__ __align__(16) _Float16 x16[M_];         // 256 (fallback)
  __shared__ __align__(16) float prevw[2 * N_];      // ww | rw
  __shared__ __align__(16) float mnv[N_];
  __shared__ __align__(16) float ksh[2 * M_];
  __shared__ __align__(16) float eah[2 * M_];
  __shared__ __align__(16) float wlog[2 * N_];
  __shared__ __align__(16) float wtmp[2 * N_];
  __shared__ __align__(16) float redU[2048];
  __shared__ __align__(16) float sdots[24];
  __shared__ __align__(16) float scal[32];
  __shared__ __align__(16) float bcL[H_];
  __shared__ __align__(16) float bkL[256];
  __shared__ __align__(16) float beL[128];
  __shared__ __align__(16) float baL[128];
  __shared__ __align__(16) float boL[128];
  __shared__ __align__(16) float sb[16];

  const int tid = threadIdx.x;
  const int b = blockIdx.x;
  const _Float16* xcg = (const _Float16*)(wsu + WS_XC);
  const uint4* wcx4 = (const uint4*)(wsu + WS_WCX);
  const uint4* wcr4 = (const uint4*)(wsu + WS_WCR);
  const uint4* w2p4 = (const uint4*)(wsu + WS_W2P);
  const uint4* wop4 = (const uint4*)(wsu + WS_WOP);
  const uint4* wsm4 = (const uint4*)(wsu + WS_WSM);
  const uint4* rp4 = (const uint4*)rd16;
  const uint4* hp4 = (const uint4*)ht16;

  // ---------- prologue ----------
  for (int i = tid; i < N_ * M_; i += NT)
    mem[(i >> 7) * MSTR + (i & 127)] = mem0[i];
  bcL[tid] = bc[tid];
  if (tid < 256) bkL[tid] = bk[tid];
  if (tid < 128) { beL[tid] = be[tid]; baL[tid] = ba[tid]; boL[tid] = bo[tid]; }
  if (tid < 12) {
    float v;
    if (tid < 2) v = bbv[tid];
    else if (tid < 4) v = bg[tid - 2];
    else if (tid < 6) v = bgm[tid - 4];
    else v = bsf[tid - 6];
    sb[tid] = v;
  }
  if (tid < 512) wlog[tid] = (tid < 256) ? ww0[tid] : rw0[tid - 256];
  __syncthreads();
  if (tid < 256) {
    float s = 0.f;
#pragma unroll 8
    for (int m = 0; m < M_; ++m) { float v = mem[tid * MSTR + m]; s += v * v; }
    mnv[tid] = fmaxf(sqrtf(s), EPSF);
  }
  {
    int wv = tid >> 6, ln = tid & 63;
    if (wv < 2) {
      float l0 = wlog[wv * N_ + ln], l1 = wlog[wv * N_ + 64 + ln],
            l2 = wlog[wv * N_ + 128 + ln], l3 = wlog[wv * N_ + 192 + ln];
      float mx = wave_rmax(fmaxf(fmaxf(l0, l1), fmaxf(l2, l3)));
      float e0 = __expf(l0 - mx), e1 = __expf(l1 - mx), e2 = __expf(l2 - mx), e3 = __expf(l3 - mx);
      float sm = wave_rsum(e0 + e1 + e2 + e3);
      wlog[wv * N_ + ln] = e0; wlog[wv * N_ + 64 + ln] = e1;
      wlog[wv * N_ + 128 + ln] = e2; wlog[wv * N_ + 192 + ln] = e3;
      if (ln == 0) scal[30 + wv] = 1.f / sm;
    }
  }
  __syncthreads();
  if (tid < 512) prevw[tid] = wlog[tid] * scal[30 + (tid >> 8)];
  if (tid < 64)
    ((unsigned*)rd16)[tid] = packh2(rd0[2 * tid], rd0[2 * tid + 1]);
  if (!useXc && tid >= 64 && tid < 128) {
    int k = tid - 64;
    ((unsigned*)x16)[k] = packh2(x[(size_t)b * I_ + 2 * k], x[(size_t)b * I_ + 2 * k + 1]);
  }
  __syncthreads();

  // ---------- time loop ----------
  for (int t = 0; t < T_; ++t) {
    // S1: phase A (h-col per thread, coalesced) + fused C12(t-1) Wo partials
    {
      const int j = tid;
      float a0, a1 = 0.f;
      if (useXc) {
        a0 = (float)xcg[((size_t)t * B_ + b) * H_ + j];
      } else {
        a0 = 0.f;
        const uint4* xp4 = (const uint4*)x16;
#pragma unroll 4
        for (int k4 = 0; k4 < 16; k4 += 2) {
          a0 = dot4(wcx4[k4 * 1024 + j], xp4[k4], a0);
          a1 = dot4(wcx4[(k4 + 1) * 1024 + j], xp4[k4 + 1], a1);
        }
      }
#pragma unroll 4
      for (int k4 = 0; k4 < 16; k4 += 2) {
        a0 = dot4(wcr4[k4 * 1024 + j], rp4[k4], a0);
        a1 = dot4(wcr4[(k4 + 1) * 1024 + j], rp4[k4 + 1], a1);
      }
      ht16[j] = (_Float16)tanhf(a0 + a1 + bcL[j]);
      if (t > 0) {           // C12(t-1): rd(t-1) @ Wo partials
        int c = tid & 127, q = tid >> 7;
        float s = dot4(wop4[(2 * q) * 128 + c], rp4[2 * q], 0.f);
        s = dot4(wop4[(2 * q + 1) * 128 + c], rp4[2 * q + 1], s);
        redU[1024 + q * 128 + c] = s;
      }
    }
    __syncthreads();

    // S3: phase B partials (thread = (c, K-half), coalesced) + out-write(t-1)
    {
      const int c = tid & 511, half = tid >> 9;
      const int kb = half * 64;
      float a0 = 0.f, a1 = 0.f, a2 = 0.f, a3 = 0.f;
#pragma unroll 8
      for (int k = 0; k < 64; k += 4) {
        a0 = dot4(w2p4[(kb + k) * 512 + c],     hp4[kb + k],     a0);
        a1 = dot4(w2p4[(kb + k + 1) * 512 + c], hp4[kb + k + 1], a1);
        a2 = dot4(w2p4[(kb + k + 2) * 512 + c], hp4[kb + k + 2], a2);
        a3 = dot4(w2p4[(kb + k + 3) * 512 + c], hp4[kb + k + 3], a3);
      }
      redU[half * 512 + c] = (a0 + a1) + (a2 + a3);
      if (tid < 128 && t > 0) {
        float o = boL[tid];
#pragma unroll
        for (int q = 0; q < 8; ++q) o += redU[1024 + q * 128 + tid];
        out[((size_t)(t - 1) * B_ + b) * I_ + tid] = o;
      }
    }
    __syncthreads();

    // S4: B finalize + activations (tid<512) | small dots (waves 8-15)
    {
      if (tid < 512) {
        float v = redU[tid] + redU[512 + tid];
        if (tid < 256)      ksh[tid] = fmaxf(v + bkL[tid], 0.f);
        else if (tid < 384) eah[tid - 256] = 1.f / (1.f + __expf(-(v + beL[tid - 256])));
        else                eah[tid - 256] = 1.f / (1.f + __expf(-(v + baL[tid - 384])));
      } else {
        int wv = (tid >> 6) - 8, ln = tid & 63;
#pragma unroll
        for (int i = 0; i < 3; ++i) {
          int hd = wv * 3 + i;           // 24 half-dots over 12 scalars
          int d = hd >> 1, half = hd & 1;
          float s = dot4(wsm4[d * 128 + half * 64 + ln], hp4[half * 64 + ln], 0.f);
          s = wave_rsum(s);
          if (ln == 0) sdots[hd] = s;
        }
      }
    }
    __syncthreads();

    // S5: scalar finalize (tid 0) | key norms (waves 1,2)
    {
      if (tid == 0) {
        for (int h = 0; h < 2; ++h) {
          float Sb = sdots[2 * h] + sdots[2 * h + 1];
          float Sg = sdots[2 * (2 + h)] + sdots[2 * (2 + h) + 1];
          float Sgm = sdots[2 * (4 + h)] + sdots[2 * (4 + h) + 1];
          float rb = Sb + sb[h];
          scal[16 + h] = (rb > 20.f) ? rb : log1pf(__expf(rb));
          scal[18 + h] = 1.f / (1.f + __expf(-(Sg + sb[2 + h])));
          scal[20 + h] = fmaxf(Sgm + sb[4 + h], 0.f) + 1.f;
          float s0 = sdots[2 * (6 + 3 * h)] + sdots[2 * (6 + 3 * h) + 1] + sb[6 + 3 * h];
          float s1 = sdots[2 * (7 + 3 * h)] + sdots[2 * (7 + 3 * h) + 1] + sb[7 + 3 * h];
          float s2 = sdots[2 * (8 + 3 * h)] + sdots[2 * (8 + 3 * h) + 1] + sb[8 + 3 * h];
          float mx = fmaxf(s0, fmaxf(s1, s2));
          float e0 = __expf(s0 - mx), e1 = __expf(s1 - mx), e2 = __expf(s2 - mx);
          float inv = 1.f / (e0 + e1 + e2);
          scal[22 + 3 * h] = e0 * inv; scal[23 + 3 * h] = e1 * inv; scal[24 + 3 * h] = e2 * inv;
        }
      } else if (tid >= 64 && tid < 192) {
        int h = (tid >> 6) - 1, ln = tid & 63;
        float v0 = ksh[h * 128 + ln], v1 = ksh[h * 128 + 64 + ln];
        float s = wave_rsum(v0 * v0 + v1 * v1);
        if (ln == 0) scal[12 + h] = fmaxf(sqrtf(s), EPSF);
      }
    }
    __syncthreads();

    // S6: cosine logits (row per lane, 8 waves; R2 pattern)
    if (tid < 512) {
      int wv = tid >> 6, ln = tid & 63;
      int h = wv & 1, n = (wv >> 1) * 64 + ln;
      const float beta = scal[16 + h], kn = scal[12 + h];
      const float4* kp = (const float4*)&ksh[h * 128];
      const float* mrow = &mem[n * MSTR];
      float dot = 0.f;
#pragma unroll 8
      for (int m4 = 0; m4 < 32; ++m4) {
        float4 kv = kp[m4];
        float4 mv = *(const float4*)&mrow[m4 * 4];
        dot += kv.x * mv.x + kv.y * mv.y + kv.z * mv.z + kv.w * mv.w;
      }
      wlog[h * N_ + n] = beta * (dot / (kn * mnv[n]));
    }
    __syncthreads();

    // S7: content softmax (waves 0,1)
    {
      int wv = tid >> 6, ln = tid & 63;
      if (wv < 2) {
        float l0 = wlog[wv * N_ + ln], l1 = wlog[wv * N_ + 64 + ln],
              l2 = wlog[wv * N_ + 128 + ln], l3 = wlog[wv * N_ + 192 + ln];
        float mx = wave_rmax(fmaxf(fmaxf(l0, l1), fmaxf(l2, l3)));
        float e0 = __expf(l0 - mx), e1 = __expf(l1 - mx), e2 = __expf(l2 - mx), e3 = __expf(l3 - mx);
        float sm = wave_rsum(e0 + e1 + e2 + e3);
        wlog[wv * N_ + ln] = e0; wlog[wv * N_ + 64 + ln] = e1;
        wlog[wv * N_ + 128 + ln] = e2; wlog[wv * N_ + 192 + ln] = e3;
        if (ln == 0) scal[30 + wv] = 1.f / sm;
      }
    }
    __syncthreads();

    // S8: interpolate
    if (tid < 512) {
      int h = tid >> 8;
      float g = scal[18 + h];
      wtmp[tid] = g * wlog[tid] * scal[30 + h] + (1.f - g) * prevw[tid];
    }
    __syncthreads();

    // S9: circular shift + sharpen
    if (tid < 512) {
      int h = tid >> 8, n = tid & 255;
      float v = scal[22 + 3 * h] * wtmp[h * N_ + ((n + 255) & 255)]
              + scal[23 + 3 * h] * wtmp[h * N_ + n]
              + scal[24 + 3 * h] * wtmp[h * N_ + ((n + 1) & 255)];
      wlog[tid] = __powf(v, scal[20 + h]);
    }
    __syncthreads();

    // S10: normalization sums
    {
      int wv = tid >> 6, ln = tid & 63;
      if (wv < 2) {
        float s = wlog[wv * N_ + ln] + wlog[wv * N_ + 64 + ln]
                + wlog[wv * N_ + 128 + ln] + wlog[wv * N_ + 192 + ln];
        s = wave_rsum(s);
        if (ln == 0) scal[14 + wv] = 1.f / s;
      }
    }
    __syncthreads();

    // S11: memory update (thread = (row, M-quarter)) + sq partials + prevw(ww)
    {
      int n = tid & 255, q = tid >> 8;
      float wwn = wlog[n] * scal[14];
      float* mrow = &mem[n * MSTR + q * 32];
      const float4* ep = (const float4*)&eah[q * 32];
      const float4* ap = (const float4*)&eah[128 + q * 32];
      float sq = 0.f;
#pragma unroll
      for (int i = 0; i < 8; ++i) {
        float4 mv = *(float4*)&mrow[i * 4];
        float4 ev = ep[i], av = ap[i];
        mv.x = mv.x * (1.f - wwn * ev.x) + wwn * av.x;
        mv.y = mv.y * (1.f - wwn * ev.y) + wwn * av.y;
        mv.z = mv.z * (1.f - wwn * ev.z) + wwn * av.z;
        mv.w = mv.w * (1.f - wwn * ev.w) + wwn * av.w;
        sq += mv.x * mv.x + mv.y * mv.y + mv.z * mv.z + mv.w * mv.w;
        *(float4*)&mrow[i * 4] = mv;
      }
      redU[1024 + q * 256 + n] = sq;
      if (q == 0) prevw[n] = wwn;
    }
    __syncthreads();

    // S12: rd partials (thread = (m, 8-way n-group); lanes = consecutive m)
    {
      int m = tid & 127, g = tid >> 7;
      const float* basep = &mem[g * 32 * MSTR + m];
      float acc = 0.f;
#pragma unroll 8
      for (int i = 0; i < 32; ++i)
        acc += wlog[256 + g * 32 + i] * basep[i * MSTR];
      redU[g * 128 + m] = acc;
    }
    __syncthreads();

    // S13: rd finalize+pack | prevw(rw) | mnv | next-x pack (fallback)
    {
      if (tid < 64) {
        float r0 = 0.f, r1 = 0.f;
#pragma unroll
        for (int g = 0; g < 8; ++g) {
          r0 += redU[g * 128 + 2 * tid];
          r1 += redU[g * 128 + 2 * tid + 1];
        }
        ((unsigned*)rd16)[tid] = packh2(r0 * scal[15], r1 * scal[15]);
      } else if (tid >= 256 && tid < 512) {
        int n = tid - 256;
        prevw[256 + n] = wlog[256 + n] * scal[15];
      } else if (tid >= 512 && tid < 768) {
        int n = tid - 512;
        float s = redU[1024 + n] + redU[1280 + n] + redU[1536 + n] + redU[1792 + n];
        mnv[n] = fmaxf(sqrtf(s), EPSF);
      } else if (!useXc && tid >= 768 && tid < 832 && t < T_ - 1) {
        int k = tid - 768;
        const float* xr = &x[((size_t)(t + 1) * B_ + b) * I_];
        ((unsigned*)x16)[k] = packh2(xr[2 * k], xr[2 * k + 1]);
      }
    }
    __syncthreads();
  }

  // ---------- epilogue: Wo for t = T-1 ----------
  {
    int c = tid & 127, q = tid >> 7;
    float s = dot4(wop4[(2 * q) * 128 + c], rp4[2 * q], 0.f);
    s = dot4(wop4[(2 * q + 1) * 128 + c], rp4[2 * q + 1], s);
    redU[1024 + q * 128 + c] = s;
  }
  __syncthreads();
  if (tid < 128) {
    float o = boL[tid];
#pragma unroll
    for (int q = 0; q < 8; ++q) o += redU[1024 + q * 128 + tid];
    out[((size_t)(T_ - 1) * B_ + b) * I_ + tid] = o;
  }
}

extern "C" void kernel_launch(void* const* d_in, const int* in_sizes, int n_in,
                              void* d_out, int out_size, void* d_ws, size_t ws_size,
                              hipStream_t stream) {
  (void)in_sizes; (void)n_in; (void)out_size;

  const float* x    = (const float*)d_in[0];
  const float* Wc   = (const float*)d_in[1];
  const float* bc   = (const float*)d_in[2];
  const float* Wk   = (const float*)d_in[3];
  const float* bk   = (const float*)d_in[4];
  const float* Wb   = (const float*)d_in[5];
  const float* bbv  = (const float*)d_in[6];
  const float* Wg   = (const float*)d_in[7];
  const float* bg   = (const float*)d_in[8];
  const float* Wsf  = (const float*)d_in[9];
  const float* bsf  = (const float*)d_in[10];
  const float* Wgm  = (const float*)d_in[11];
  const float* bgm  = (const float*)d_in[12];
  const float* We   = (const float*)d_in[13];
  const float* be   = (const float*)d_in[14];
  const float* Wa   = (const float*)d_in[15];
  const float* ba   = (const float*)d_in[16];
  const float* Wo   = (const float*)d_in[17];
  const float* bo   = (const float*)d_in[18];
  const float* mem0 = (const float*)d_in[19];
  const float* ww0  = (const float*)d_in[20];
  const float* rw0  = (const float*)d_in[21];
  const float* rd0  = (const float*)d_in[22];
  float* out = (float*)d_out;
  unsigned* wsu = (unsigned*)d_ws;

  const int useXc = (ws_size >= WS_BYTES_NEEDED) ? 1 : 0;

  ntm_pack<<<dim3(512), dim3(256), 0, stream>>>(Wc, Wk, Wb, Wg, Wsf, Wgm, We, Wa, Wo, wsu);
  if (useXc)
    ntm_xc<<<dim3(T_ * B_ / 16), dim3(256), 0, stream>>>(x, wsu, wsu);
  ntm_main<<<dim3(NB), dim3(NT), 0, stream>>>(x, bc, bk, bbv, bg, bsf, bgm, be, ba, bo,
                                              mem0, ww0, rw0, rd0, wsu, out, useXc);
}